// Round 6
// baseline (9638.033 us; speedup 1.0000x reference)
//
#include <hip/hip_runtime.h>
#include <stdint.h>

#define ALPHA 64
#define EDIM 1024
#define G4 4096
#define BATCH 4096
#define TLEN 20
#define BOS_TOK 64
#define PAD_TOK 65
#define EOS_TOK 0

// ---------------------------------------------------------------------------
// Threefry-2x32, 20 rounds — exact transcription of jax/_src/prng.py
// ---------------------------------------------------------------------------
__device__ __forceinline__ void threefry2x32(uint32_t k0, uint32_t k1,
                                             uint32_t& x0, uint32_t& x1) {
  uint32_t ks[3] = {k0, k1, k0 ^ k1 ^ 0x1BD11BDAu};
  const int rot0[4] = {13, 15, 26, 6};
  const int rot1[4] = {17, 29, 16, 24};
  x0 += ks[0];
  x1 += ks[1];
#pragma unroll
  for (int i = 0; i < 5; ++i) {
    const int* rr = (i & 1) ? rot1 : rot0;
#pragma unroll
    for (int j = 0; j < 4; ++j) {
      x0 += x1;
      x1 = (x1 << rr[j]) | (x1 >> (32 - rr[j]));
      x1 ^= x0;
    }
    x0 += ks[(i + 1) % 3];
    x1 += ks[(i + 2) % 3] + (uint32_t)(i + 1);
  }
}

// ---------------------------------------------------------------------------
// jax_threefry_partitionable=True (default since jax 0.4.30) semantics:
//   split(key, 20) foldlike: keys[t] = threefry(key, (hi=0, lo=t)) -> (x0', x1')
//   random_bits 32-bit:      bits[m] = x0' ^ x1' of threefry(key, (hi=0, lo=m))
// ---------------------------------------------------------------------------
__global__ void init_kernel(uint32_t* __restrict__ keyA, uint32_t* __restrict__ keyB,
                            int* __restrict__ last, int* __restrict__ stopped,
                            double* __restrict__ ent_sum, int* __restrict__ len_sum) {
  int i = blockIdx.x * 256 + threadIdx.x;
  if (i < BATCH) {
    last[i] = BOS_TOK;
    stopped[i] = 0;
    ent_sum[i] = 0.0;
    len_sum[i] = 0;
  }
  if (i < TLEN) {
    uint32_t x0 = 0u, x1 = (uint32_t)i;   // 64-bit iota elem i -> (hi=0, lo=i)
    threefry2x32(0u, 42u, x0, x1);        // key(42) = (0, 42)
    keyA[i] = x0;
    keyB[i] = x1;
  }
}

// W_act [64][1024] -> WactT [1024][64]
__global__ void transpose_wact(const float* __restrict__ W, float* __restrict__ Wt) {
  int i = blockIdx.x * 256 + threadIdx.x;
  if (i < ALPHA * EDIM) {
    int a = i >> 10, k = i & 1023;
    Wt[(size_t)k * ALPHA + a] = W[i];
  }
}

// ---------------------------------------------------------------------------
// f32 NT GEMM (init path): C = A@B^T (+bias1[n] if non-null)
// Single-accumulator ascending-k fmaf chain per element (numerics anchor).
// 128x128 tile, BK=16, 256 threads, 8x8 per thread
// ---------------------------------------------------------------------------
__global__ __launch_bounds__(256) void gemm_nt0(
    const float* __restrict__ A, const float* __restrict__ Bw, float* __restrict__ C,
    int M, int N, int K, const float* __restrict__ bias1) {
  __shared__ float As[16][132];
  __shared__ float Bs[16][132];
  const int t = threadIdx.x;
  const int bm = blockIdx.y * 128;
  const int bn = blockIdx.x * 128;
  const int tx = t & 15, ty = t >> 4;

  float acc[8][8];
#pragma unroll
  for (int i = 0; i < 8; ++i)
#pragma unroll
    for (int j = 0; j < 8; ++j) acc[i][j] = 0.0f;

  const int sr = t >> 1;          // 0..127 (tile row)
  const int sc = (t & 1) << 3;    // 0 or 8 (k offset)
  const float* ap = A + (size_t)(bm + sr) * K + sc;
  const float* bp = Bw + (size_t)(bn + sr) * K + sc;
  const bool aok = (bm + sr) < M;

  for (int k0 = 0; k0 < K; k0 += 16) {
    float4 av0 = {0.f, 0.f, 0.f, 0.f}, av1 = {0.f, 0.f, 0.f, 0.f};
    if (aok) {
      av0 = *(const float4*)(ap + k0);
      av1 = *(const float4*)(ap + k0 + 4);
    }
    float4 bv0 = *(const float4*)(bp + k0);
    float4 bv1 = *(const float4*)(bp + k0 + 4);
    __syncthreads();
    As[sc + 0][sr] = av0.x; As[sc + 1][sr] = av0.y; As[sc + 2][sr] = av0.z; As[sc + 3][sr] = av0.w;
    As[sc + 4][sr] = av1.x; As[sc + 5][sr] = av1.y; As[sc + 6][sr] = av1.z; As[sc + 7][sr] = av1.w;
    Bs[sc + 0][sr] = bv0.x; Bs[sc + 1][sr] = bv0.y; Bs[sc + 2][sr] = bv0.z; Bs[sc + 3][sr] = bv0.w;
    Bs[sc + 4][sr] = bv1.x; Bs[sc + 5][sr] = bv1.y; Bs[sc + 6][sr] = bv1.z; Bs[sc + 7][sr] = bv1.w;
    __syncthreads();
#pragma unroll
    for (int k = 0; k < 16; ++k) {
      float4 a0 = *(const float4*)&As[k][ty * 4];
      float4 a1 = *(const float4*)&As[k][ty * 4 + 64];
      float4 b0 = *(const float4*)&Bs[k][tx * 4];
      float4 b1 = *(const float4*)&Bs[k][tx * 4 + 64];
      float ar[8] = {a0.x, a0.y, a0.z, a0.w, a1.x, a1.y, a1.z, a1.w};
      float br[8] = {b0.x, b0.y, b0.z, b0.w, b1.x, b1.y, b1.z, b1.w};
#pragma unroll
      for (int i = 0; i < 8; ++i)
#pragma unroll
        for (int j = 0; j < 8; ++j) acc[i][j] = fmaf(ar[i], br[j], acc[i][j]);
    }
  }

#pragma unroll
  for (int i = 0; i < 8; ++i) {
    int mG = bm + ty * 4 + (i & 3) + ((i >> 2) << 6);
    if (mG >= M) continue;
#pragma unroll
    for (int j = 0; j < 8; ++j) {
      int nG = bn + tx * 4 + (j & 3) + ((j >> 2) << 6);
      float v = acc[i][j];
      if (bias1) v = __fadd_rn(v, bias1[nG]);
      C[(size_t)mG * N + nG] = v;
    }
  }
}

// ---------------------------------------------------------------------------
// FUSED gates-GEMM + LSTM pointwise.
// Tile: 128 rows x 32 j's x 4 gates (=128 LDS cols). LDS col c holds
// W_hh row (c&3)*1024 + j0 + (c>>2), so thread (tx,ty)'s 8 cols =
// {tx*4+g, tx*4+64+g} = all 4 gates of j = j0+tx and j0+tx+16.
// Per-element math: identical ascending-k fmaf chain + identical epilogue
// op sequence as the verified round-5 kernel (bit-exact).
// Register prefetch of chunk k+1 hides global latency under the FMA phase.
// Reads h_old (A), RMWs c, writes h_new (double-buffered h: no race).
// ---------------------------------------------------------------------------
__global__ __launch_bounds__(256) void gemm_lstm_fused(
    const float* __restrict__ A, const float* __restrict__ Bw,
    const float* __restrict__ eg, const int* __restrict__ lastIdx,
    const float* __restrict__ b_ih, const float* __restrict__ b_hh,
    float* __restrict__ hN, float* __restrict__ cst) {
  __shared__ float As[16][132];
  __shared__ float Bs[16][132];
  const int t = threadIdx.x;
  const int bm = blockIdx.y * 128;   // row block
  const int j0 = blockIdx.x * 32;    // j block
  const int tx = t & 15, ty = t >> 4;

  float acc[8][8];
#pragma unroll
  for (int i = 0; i < 8; ++i)
#pragma unroll
    for (int j = 0; j < 8; ++j) acc[i][j] = 0.0f;

  const int sr = t >> 1;          // 0..127 (LDS col for B / tile row for A)
  const int sc = (t & 1) << 3;    // 0 or 8 (k offset)
  const float* ap = A + (size_t)(bm + sr) * EDIM + sc;
  // B LDS col sr <- W_hh row (sr&3)*1024 + j0 + (sr>>2)
  const float* bp = Bw + (size_t)((sr & 3) * EDIM + j0 + (sr >> 2)) * EDIM + sc;

  // prologue: prefetch chunk 0
  float4 av0 = *(const float4*)(ap);
  float4 av1 = *(const float4*)(ap + 4);
  float4 bv0 = *(const float4*)(bp);
  float4 bv1 = *(const float4*)(bp + 4);

  for (int k0 = 0; k0 < EDIM; k0 += 16) {
    __syncthreads();
    As[sc + 0][sr] = av0.x; As[sc + 1][sr] = av0.y; As[sc + 2][sr] = av0.z; As[sc + 3][sr] = av0.w;
    As[sc + 4][sr] = av1.x; As[sc + 5][sr] = av1.y; As[sc + 6][sr] = av1.z; As[sc + 7][sr] = av1.w;
    Bs[sc + 0][sr] = bv0.x; Bs[sc + 1][sr] = bv0.y; Bs[sc + 2][sr] = bv0.z; Bs[sc + 3][sr] = bv0.w;
    Bs[sc + 4][sr] = bv1.x; Bs[sc + 5][sr] = bv1.y; Bs[sc + 6][sr] = bv1.z; Bs[sc + 7][sr] = bv1.w;
    if (k0 + 16 < EDIM) {   // prefetch next chunk; hides latency under compute
      av0 = *(const float4*)(ap + k0 + 16);
      av1 = *(const float4*)(ap + k0 + 20);
      bv0 = *(const float4*)(bp + k0 + 16);
      bv1 = *(const float4*)(bp + k0 + 20);
    }
    __syncthreads();
#pragma unroll
    for (int k = 0; k < 16; ++k) {
      float4 a0 = *(const float4*)&As[k][ty * 4];
      float4 a1 = *(const float4*)&As[k][ty * 4 + 64];
      float4 b0 = *(const float4*)&Bs[k][tx * 4];
      float4 b1 = *(const float4*)&Bs[k][tx * 4 + 64];
      float ar[8] = {a0.x, a0.y, a0.z, a0.w, a1.x, a1.y, a1.z, a1.w};
      float br[8] = {b0.x, b0.y, b0.z, b0.w, b1.x, b1.y, b1.z, b1.w};
#pragma unroll
      for (int i = 0; i < 8; ++i)
#pragma unroll
        for (int j = 0; j < 8; ++j) acc[i][j] = fmaf(ar[i], br[j], acc[i][j]);
    }
  }

  // Fused epilogue: gates -> c2/h2, bit-identical op sequence to the
  // verified (gemm epilogue + lstm_pointwise) pair.
#pragma unroll
  for (int i = 0; i < 8; ++i) {
    const int row = bm + ty * 4 + (i & 3) + ((i >> 2) << 6);
    const float* egrow = eg + (size_t)lastIdx[row] * G4;
#pragma unroll
    for (int jj = 0; jj < 2; ++jj) {
      const int jg = j0 + tx + jj * 16;
      float gv[4];
#pragma unroll
      for (int g = 0; g < 4; ++g) {
        const int n = g * EDIM + jg;
        const float bsum = __fadd_rn(b_ih[n], b_hh[n]);
        gv[g] = __fadd_rn(__fadd_rn(egrow[n], acc[i][jj * 4 + g]), bsum);
      }
      const size_t idx = (size_t)row * EDIM + jg;
      float cc = cst[idx];
      float si = 1.0f / (__fadd_rn(1.0f, expf(-gv[0])));
      float sf = 1.0f / (__fadd_rn(1.0f, expf(-gv[1])));
      float so = 1.0f / (__fadd_rn(1.0f, expf(-gv[3])));
      float c2 = __fadd_rn(__fmul_rn(sf, cc), __fmul_rn(si, tanhf(gv[2])));
      float h2 = __fmul_rn(so, tanhf(c2));
      cst[idx] = c2;
      hN[idx] = h2;
    }
  }
}

// ---------------------------------------------------------------------------
// logits (h2 @ W_act^T + b_act) + gumbel-max sampling + log_softmax + stats.
// All f32, ascending-k fmaf chain for the logit dot.
// Block = 256 threads = 4 waves; 8 batch rows per block (2 per wave, lane=class).
// ---------------------------------------------------------------------------
__global__ __launch_bounds__(256) void logits_sample(
    const float* __restrict__ h, const float* __restrict__ Wt,
    const float* __restrict__ b_act,
    const uint32_t* __restrict__ keyA, const uint32_t* __restrict__ keyB, int tstep,
    int* __restrict__ last, int* __restrict__ stopped,
    double* __restrict__ ent_sum, int* __restrict__ len_sum,
    float* __restrict__ out_lp, float* __restrict__ out_msg) {
  __shared__ float Ws[64][64];  // [k-in-panel][class]
  __shared__ float Hs[8][64];   // [local row][k-in-panel]
  const int tid = threadIdx.x;
  const int wave = tid >> 6;
  const int lane = tid & 63;
  const int rowBase = blockIdx.x * 8;

  float acc0 = 0.0f, acc1 = 0.0f;
  for (int kp = 0; kp < EDIM; kp += 64) {
    __syncthreads();
    {  // stage W panel (4096 floats)
      const float4* src = (const float4*)(Wt + (size_t)kp * ALPHA);
      float4* dst = (float4*)&Ws[0][0];
#pragma unroll
      for (int q = 0; q < 4; ++q) dst[tid + q * 256] = src[tid + q * 256];
    }
    if (tid < 128) {  // stage 8 h-rows x 64 k
      int rr = tid >> 4;
      int cc = (tid & 15) << 2;
      *(float4*)&Hs[rr][cc] = *(const float4*)(h + (size_t)(rowBase + rr) * EDIM + kp + cc);
    }
    __syncthreads();
#pragma unroll
    for (int kk = 0; kk < 64; ++kk) {   // ascending k
      float w = Ws[kk][lane];
      acc0 = fmaf(Hs[wave * 2 + 0][kk], w, acc0);
      acc1 = fmaf(Hs[wave * 2 + 1][kk], w, acc1);
    }
  }

  const float ba = b_act[lane];
  const uint32_t k0 = keyA[tstep], k1 = keyB[tstep];
  float logitv[2] = {__fadd_rn(acc0, ba), __fadd_rn(acc1, ba)};

#pragma unroll
  for (int rsel = 0; rsel < 2; ++rsel) {
    const int b = rowBase + wave * 2 + rsel;
    const float logit = logitv[rsel];

    // --- partitionable random_bits: elem m -> threefry(key, (0, m)), xor halves
    uint32_t m = ((uint32_t)b << 6) | (uint32_t)lane;
    uint32_t x0 = 0u, x1 = m;
    threefry2x32(k0, k1, x0, x1);
    uint32_t bits = x0 ^ x1;

    // bit-exact f32 uniform per jax: (bits>>9 | 1.0f) - 1; u = max(tiny, f+tiny)
    float f = __fsub_rn(__uint_as_float((bits >> 9) | 0x3F800000u), 1.0f);
    const float TINY = 1.17549435e-38f;
    float u = fmaxf(TINY, __fadd_rn(f, TINY));
    float gmb = -logf(-logf(u));
    float z = __fadd_rn(logit, gmb);

    // argmax (first index on ties)
    float bv = z;
    int bi = lane;
#pragma unroll
    for (int off = 32; off > 0; off >>= 1) {
      float ov = __shfl_xor(bv, off, 64);
      int oi = __shfl_xor(bi, off, 64);
      if (ov > bv || (ov == bv && oi < bi)) { bv = ov; bi = oi; }
    }

    // log_softmax: shifted - log(sum(exp(shifted)))
    float mx = logit;
#pragma unroll
    for (int off = 32; off > 0; off >>= 1) mx = fmaxf(mx, __shfl_xor(mx, off, 64));
    float sh = __fsub_rn(logit, mx);
    float e = expf(sh);
    float s = e;
#pragma unroll
    for (int off = 32; off > 0; off >>= 1) s = __fadd_rn(s, __shfl_xor(s, off, 64));
    float ls = logf(s);
    float logp = __fsub_rn(sh, ls);

    // entropy term: -sum(exp(logp)*logp)
    float term = __fmul_rn(expf(logp), logp);
    float ts = term;
#pragma unroll
    for (int off = 32; off > 0; off >>= 1) ts = __fadd_rn(ts, __shfl_xor(ts, off, 64));

    float lp_taken = __shfl(logp, bi, 64);  // uses UNMASKED sampled action

    int st = stopped[b];
    float live = st ? 0.0f : 1.0f;
    int act = st ? PAD_TOK : bi;
    int st2 = (st || act == EOS_TOK) ? 1 : 0;

    if (lane == 0) {
      out_msg[(size_t)b * TLEN + tstep] = (float)act;
      out_lp[(size_t)b * TLEN + tstep] = __fmul_rn(lp_taken, live);
      ent_sum[b] += (double)__fmul_rn(-ts, live);
      len_sum[b] += (act != PAD_TOK) ? 1 : 0;
      last[b] = act;
      stopped[b] = st2;
    }
  }
}

__global__ void finalize_kernel(const double* __restrict__ ent_sum,
                                const int* __restrict__ len_sum,
                                float* __restrict__ out_ent, float* __restrict__ out_len) {
  int b = blockIdx.x * 256 + threadIdx.x;
  if (b < BATCH) {
    out_ent[b] = (float)(ent_sum[b] / (double)len_sum[b]);
    out_len[b] = (float)len_sum[b];
  }
}

// ---------------------------------------------------------------------------
extern "C" void kernel_launch(void* const* d_in, const int* in_sizes, int n_in,
                              void* d_out, int out_size, void* d_ws, size_t ws_size,
                              hipStream_t stream) {
  const float* encoded = (const float*)d_in[0];
  const float* embed = (const float*)d_in[1];
  const float* W_ih = (const float*)d_in[2];
  const float* W_hh = (const float*)d_in[3];
  const float* b_ih = (const float*)d_in[4];
  const float* b_hh = (const float*)d_in[5];
  const float* W_cell = (const float*)d_in[6];
  const float* b_cell = (const float*)d_in[7];
  const float* W_hid = (const float*)d_in[8];
  const float* b_hid = (const float*)d_in[9];
  const float* W_act = (const float*)d_in[10];
  const float* b_act = (const float*)d_in[11];

  float* out = (float*)d_out;
  float* out_ent = out;                           // [4096]
  float* out_lp = out + BATCH;                    // [4096*20]
  float* out_msg = out + BATCH + BATCH * TLEN;    // [4096*20]
  float* out_len = out + BATCH + 2 * BATCH * TLEN;// [4096]

  char* ws = (char*)d_ws;
  size_t off = 0;
  auto alloc = [&](size_t bytes) -> void* {
    void* p = ws + off;
    off = (off + bytes + 255) & ~(size_t)255;
    return p;
  };
  float* h0b = (float*)alloc(sizeof(float) * (size_t)BATCH * EDIM);     // 16 MB
  float* h1b = (float*)alloc(sizeof(float) * (size_t)BATCH * EDIM);     // 16 MB
  float* c = (float*)alloc(sizeof(float) * (size_t)BATCH * EDIM);       // 16 MB
  float* eg = (float*)alloc(sizeof(float) * 66 * G4);                   // 1 MB (raw s1)
  float* Wt = (float*)alloc(sizeof(float) * EDIM * ALPHA);              // 256 KB
  uint32_t* keyA = (uint32_t*)alloc(sizeof(uint32_t) * TLEN);
  uint32_t* keyB = (uint32_t*)alloc(sizeof(uint32_t) * TLEN);
  int* last = (int*)alloc(sizeof(int) * BATCH);
  int* stopped = (int*)alloc(sizeof(int) * BATCH);
  double* ent_s = (double*)alloc(sizeof(double) * BATCH);
  int* len_s = (int*)alloc(sizeof(int) * BATCH);
  (void)ws_size; (void)in_sizes; (void)n_in; (void)out_size;

  init_kernel<<<16, 256, 0, stream>>>(keyA, keyB, last, stopped, ent_s, len_s);
  transpose_wact<<<(ALPHA * EDIM) / 256, 256, 0, stream>>>(W_act, Wt);

  // s1 table: eg = embed @ W_ih^T  (NO bias — ref adds bias after both gemms)
  gemm_nt0<<<dim3(32, 1), 256, 0, stream>>>(embed, W_ih, eg, 66, G4, EDIM, nullptr);
  // h0 = encoded @ W_cell^T + b_cell ; c0 = encoded @ W_hid^T + b_hid
  gemm_nt0<<<dim3(8, 32), 256, 0, stream>>>(encoded, W_cell, h0b, BATCH, EDIM, EDIM, b_cell);
  gemm_nt0<<<dim3(8, 32), 256, 0, stream>>>(encoded, W_hid, c, BATCH, EDIM, EDIM, b_hid);

  float* hb[2] = {h0b, h1b};
  for (int t = 0; t < TLEN; ++t) {
    const float* hin = hb[t & 1];
    float* hout = hb[(t & 1) ^ 1];
    // gates = (eg[last] + hin @ W_hh^T) + (b_ih + b_hh) -> LSTM -> hout, c
    gemm_lstm_fused<<<dim3(32, 32), 256, 0, stream>>>(hin, W_hh, eg, last,
                                                      b_ih, b_hh, hout, c);
    logits_sample<<<BATCH / 8, 256, 0, stream>>>(hout, Wt, b_act, keyA, keyB, t,
                                                 last, stopped, ent_s, len_s,
                                                 out_lp, out_msg);
  }
  finalize_kernel<<<16, 256, 0, stream>>>(ent_s, len_s, out_ent, out_len);
}

// Round 7
// 8878.532 us; speedup vs baseline: 1.0855x; 1.0855x over previous
//
#include <hip/hip_runtime.h>
#include <stdint.h>

#define ALPHA 64
#define EDIM 1024
#define G4 4096
#define BATCH 4096
#define TLEN 20
#define BOS_TOK 64
#define PAD_TOK 65
#define EOS_TOK 0

// ---------------------------------------------------------------------------
// Threefry-2x32, 20 rounds — exact transcription of jax/_src/prng.py
// ---------------------------------------------------------------------------
__device__ __forceinline__ void threefry2x32(uint32_t k0, uint32_t k1,
                                             uint32_t& x0, uint32_t& x1) {
  uint32_t ks[3] = {k0, k1, k0 ^ k1 ^ 0x1BD11BDAu};
  const int rot0[4] = {13, 15, 26, 6};
  const int rot1[4] = {17, 29, 16, 24};
  x0 += ks[0];
  x1 += ks[1];
#pragma unroll
  for (int i = 0; i < 5; ++i) {
    const int* rr = (i & 1) ? rot1 : rot0;
#pragma unroll
    for (int j = 0; j < 4; ++j) {
      x0 += x1;
      x1 = (x1 << rr[j]) | (x1 >> (32 - rr[j]));
      x1 ^= x0;
    }
    x0 += ks[(i + 1) % 3];
    x1 += ks[(i + 2) % 3] + (uint32_t)(i + 1);
  }
}

// ---------------------------------------------------------------------------
// jax_threefry_partitionable=True (default since jax 0.4.30) semantics:
//   split(key, 20) foldlike: keys[t] = threefry(key, (hi=0, lo=t)) -> (x0', x1')
//   random_bits 32-bit:      bits[m] = x0' ^ x1' of threefry(key, (hi=0, lo=m))
// ---------------------------------------------------------------------------
__global__ void init_kernel(uint32_t* __restrict__ keyA, uint32_t* __restrict__ keyB,
                            int* __restrict__ last, int* __restrict__ stopped,
                            double* __restrict__ ent_sum, int* __restrict__ len_sum,
                            int* __restrict__ cnt) {
  int i = blockIdx.x * 256 + threadIdx.x;
  if (i < BATCH) {
    last[i] = BOS_TOK;
    stopped[i] = 0;
    ent_sum[i] = 0.0;
    len_sum[i] = 0;
  }
  if (i < TLEN) {
    uint32_t x0 = 0u, x1 = (uint32_t)i;   // 64-bit iota elem i -> (hi=0, lo=i)
    threefry2x32(0u, 42u, x0, x1);        // key(42) = (0, 42)
    keyA[i] = x0;
    keyB[i] = x1;
    cnt[i] = 0;
  }
}

// Compact indices of alive (not stopped) rows. Order nondeterministic —
// harmless: every row's math is independent and identical regardless of
// its position in the list.
__global__ void compact_alive(const int* __restrict__ stopped,
                              int* __restrict__ aliveIdx, int* __restrict__ cnt,
                              int t) {
  int i = blockIdx.x * 256 + threadIdx.x;
  if (i < BATCH && !stopped[i]) {
    int p = atomicAdd(&cnt[t], 1);
    aliveIdx[p] = i;
  }
}

// W_act [64][1024] -> WactT [1024][64]
__global__ void transpose_wact(const float* __restrict__ W, float* __restrict__ Wt) {
  int i = blockIdx.x * 256 + threadIdx.x;
  if (i < ALPHA * EDIM) {
    int a = i >> 10, k = i & 1023;
    Wt[(size_t)k * ALPHA + a] = W[i];
  }
}

// ---------------------------------------------------------------------------
// f32 NT GEMM (init path): C = A@B^T (+bias1[n] if non-null)
// Single-accumulator ascending-k fmaf chain per element (numerics anchor).
// 128x128 tile, BK=16, 256 threads, 8x8 per thread
// ---------------------------------------------------------------------------
__global__ __launch_bounds__(256) void gemm_nt0(
    const float* __restrict__ A, const float* __restrict__ Bw, float* __restrict__ C,
    int M, int N, int K, const float* __restrict__ bias1) {
  __shared__ float As[16][132];
  __shared__ float Bs[16][132];
  const int t = threadIdx.x;
  const int bm = blockIdx.y * 128;
  const int bn = blockIdx.x * 128;
  const int tx = t & 15, ty = t >> 4;

  float acc[8][8];
#pragma unroll
  for (int i = 0; i < 8; ++i)
#pragma unroll
    for (int j = 0; j < 8; ++j) acc[i][j] = 0.0f;

  const int sr = t >> 1;          // 0..127 (tile row)
  const int sc = (t & 1) << 3;    // 0 or 8 (k offset)
  const float* ap = A + (size_t)(bm + sr) * K + sc;
  const float* bp = Bw + (size_t)(bn + sr) * K + sc;
  const bool aok = (bm + sr) < M;

  for (int k0 = 0; k0 < K; k0 += 16) {
    float4 av0 = {0.f, 0.f, 0.f, 0.f}, av1 = {0.f, 0.f, 0.f, 0.f};
    if (aok) {
      av0 = *(const float4*)(ap + k0);
      av1 = *(const float4*)(ap + k0 + 4);
    }
    float4 bv0 = *(const float4*)(bp + k0);
    float4 bv1 = *(const float4*)(bp + k0 + 4);
    __syncthreads();
    As[sc + 0][sr] = av0.x; As[sc + 1][sr] = av0.y; As[sc + 2][sr] = av0.z; As[sc + 3][sr] = av0.w;
    As[sc + 4][sr] = av1.x; As[sc + 5][sr] = av1.y; As[sc + 6][sr] = av1.z; As[sc + 7][sr] = av1.w;
    Bs[sc + 0][sr] = bv0.x; Bs[sc + 1][sr] = bv0.y; Bs[sc + 2][sr] = bv0.z; Bs[sc + 3][sr] = bv0.w;
    Bs[sc + 4][sr] = bv1.x; Bs[sc + 5][sr] = bv1.y; Bs[sc + 6][sr] = bv1.z; Bs[sc + 7][sr] = bv1.w;
    __syncthreads();
#pragma unroll
    for (int k = 0; k < 16; ++k) {
      float4 a0 = *(const float4*)&As[k][ty * 4];
      float4 a1 = *(const float4*)&As[k][ty * 4 + 64];
      float4 b0 = *(const float4*)&Bs[k][tx * 4];
      float4 b1 = *(const float4*)&Bs[k][tx * 4 + 64];
      float ar[8] = {a0.x, a0.y, a0.z, a0.w, a1.x, a1.y, a1.z, a1.w};
      float br[8] = {b0.x, b0.y, b0.z, b0.w, b1.x, b1.y, b1.z, b1.w};
#pragma unroll
      for (int i = 0; i < 8; ++i)
#pragma unroll
        for (int j = 0; j < 8; ++j) acc[i][j] = fmaf(ar[i], br[j], acc[i][j]);
    }
  }

#pragma unroll
  for (int i = 0; i < 8; ++i) {
    int mG = bm + ty * 4 + (i & 3) + ((i >> 2) << 6);
    if (mG >= M) continue;
#pragma unroll
    for (int j = 0; j < 8; ++j) {
      int nG = bn + tx * 4 + (j & 3) + ((j >> 2) << 6);
      float v = acc[i][j];
      if (bias1) v = __fadd_rn(v, bias1[nG]);
      C[(size_t)mG * N + nG] = v;
    }
  }
}

// ---------------------------------------------------------------------------
// Gates GEMM on COMPACTED alive rows: identical math/structure to the
// verified round-5 MODE-1 kernel; only row addressing goes through aliveIdx.
// gates[row] = (eg[last[row]] + h[row] @ W_hh^T) + (b_ih + b_hh)
// ---------------------------------------------------------------------------
__global__ __launch_bounds__(256) void gemm_gates(
    const float* __restrict__ A, const float* __restrict__ Bw, float* __restrict__ C,
    const float* __restrict__ bias1, const float* __restrict__ bias2,
    const float* __restrict__ eg, const int* __restrict__ lastIdx,
    const int* __restrict__ aliveIdx, const int* __restrict__ aliveCnt) {
  const int an = *aliveCnt;
  const int bm = blockIdx.y * 128;
  if (bm >= an) return;            // whole block beyond alive range: dead work
  __shared__ float As[16][132];
  __shared__ float Bs[16][132];
  const int t = threadIdx.x;
  const int bn = blockIdx.x * 128;
  const int tx = t & 15, ty = t >> 4;

  float acc[8][8];
#pragma unroll
  for (int i = 0; i < 8; ++i)
#pragma unroll
    for (int j = 0; j < 8; ++j) acc[i][j] = 0.0f;

  const int sr = t >> 1;          // 0..127 (tile row / LDS col)
  const int sc = (t & 1) << 3;    // 0 or 8 (k offset)
  const int lp = bm + sr;         // position in alive list
  const int arow = (lp < an) ? aliveIdx[lp] : 0;   // dummy row 0 if past end
  const float* ap = A + (size_t)arow * EDIM + sc;
  const float* bp = Bw + (size_t)(bn + sr) * EDIM + sc;

  for (int k0 = 0; k0 < EDIM; k0 += 16) {
    float4 av0 = *(const float4*)(ap + k0);
    float4 av1 = *(const float4*)(ap + k0 + 4);
    float4 bv0 = *(const float4*)(bp + k0);
    float4 bv1 = *(const float4*)(bp + k0 + 4);
    __syncthreads();
    As[sc + 0][sr] = av0.x; As[sc + 1][sr] = av0.y; As[sc + 2][sr] = av0.z; As[sc + 3][sr] = av0.w;
    As[sc + 4][sr] = av1.x; As[sc + 5][sr] = av1.y; As[sc + 6][sr] = av1.z; As[sc + 7][sr] = av1.w;
    Bs[sc + 0][sr] = bv0.x; Bs[sc + 1][sr] = bv0.y; Bs[sc + 2][sr] = bv0.z; Bs[sc + 3][sr] = bv0.w;
    Bs[sc + 4][sr] = bv1.x; Bs[sc + 5][sr] = bv1.y; Bs[sc + 6][sr] = bv1.z; Bs[sc + 7][sr] = bv1.w;
    __syncthreads();
#pragma unroll
    for (int k = 0; k < 16; ++k) {
      float4 a0 = *(const float4*)&As[k][ty * 4];
      float4 a1 = *(const float4*)&As[k][ty * 4 + 64];
      float4 b0 = *(const float4*)&Bs[k][tx * 4];
      float4 b1 = *(const float4*)&Bs[k][tx * 4 + 64];
      float ar[8] = {a0.x, a0.y, a0.z, a0.w, a1.x, a1.y, a1.z, a1.w};
      float br[8] = {b0.x, b0.y, b0.z, b0.w, b1.x, b1.y, b1.z, b1.w};
#pragma unroll
      for (int i = 0; i < 8; ++i)
#pragma unroll
        for (int j = 0; j < 8; ++j) acc[i][j] = fmaf(ar[i], br[j], acc[i][j]);
    }
  }

#pragma unroll
  for (int i = 0; i < 8; ++i) {
    const int mlp = bm + ty * 4 + (i & 3) + ((i >> 2) << 6);
    if (mlp >= an) continue;
    const int row = aliveIdx[mlp];
    const float* egrow = eg + (size_t)lastIdx[row] * G4;
#pragma unroll
    for (int j = 0; j < 8; ++j) {
      int nG = bn + tx * 4 + (j & 3) + ((j >> 2) << 6);
      // ref: (x@W_ih.T + h@W_hh.T) + (b_ih + b_hh), each add rounded once
      float bsum = __fadd_rn(bias1[nG], bias2[nG]);
      float v = __fadd_rn(__fadd_rn(egrow[nG], acc[i][j]), bsum);
      C[(size_t)row * G4 + nG] = v;
    }
  }
}

// ---------------------------------------------------------------------------
// LSTM pointwise on compacted alive rows, pure f32, explicit rn ops.
// gate order i,f,g,o; c2=sig(f)*c+sig(i)*tanh(g); h2=sig(o)*tanh(c2)
// ---------------------------------------------------------------------------
__global__ __launch_bounds__(256) void lstm_pointwise(const float* __restrict__ gates,
                                                      float* __restrict__ h,
                                                      float* __restrict__ c,
                                                      const int* __restrict__ aliveIdx,
                                                      const int* __restrict__ aliveCnt) {
  int idx = blockIdx.x * 256 + threadIdx.x;
  int lp = idx >> 10, jj = idx & 1023;
  if (lp >= *aliveCnt) return;
  int row = aliveIdx[lp];
  const float* grow = gates + ((size_t)row << 12);
  float gi = grow[jj];
  float gf = grow[jj + 1024];
  float gg = grow[jj + 2048];
  float go = grow[jj + 3072];
  size_t cidx = ((size_t)row << 10) + jj;
  float cc = c[cidx];
  float si = 1.0f / (__fadd_rn(1.0f, expf(-gi)));
  float sf = 1.0f / (__fadd_rn(1.0f, expf(-gf)));
  float so = 1.0f / (__fadd_rn(1.0f, expf(-go)));
  float c2 = __fadd_rn(__fmul_rn(sf, cc), __fmul_rn(si, tanhf(gg)));
  float h2 = __fmul_rn(so, tanhf(c2));
  c[cidx] = c2;
  h[cidx] = h2;
}

// ---------------------------------------------------------------------------
// logits (h2 @ W_act^T + b_act) + gumbel-max sampling + log_softmax + stats.
// All f32, ascending-k fmaf chain for the logit dot.
// Block = 256 threads = 4 waves; 8 batch rows per block (2 per wave, lane=class).
// Stopped rows use stale h — their outputs are masked, so it cannot matter.
// ---------------------------------------------------------------------------
__global__ __launch_bounds__(256) void logits_sample(
    const float* __restrict__ h, const float* __restrict__ Wt,
    const float* __restrict__ b_act,
    const uint32_t* __restrict__ keyA, const uint32_t* __restrict__ keyB, int tstep,
    int* __restrict__ last, int* __restrict__ stopped,
    double* __restrict__ ent_sum, int* __restrict__ len_sum,
    float* __restrict__ out_lp, float* __restrict__ out_msg) {
  __shared__ float Ws[64][64];  // [k-in-panel][class]
  __shared__ float Hs[8][64];   // [local row][k-in-panel]
  const int tid = threadIdx.x;
  const int wave = tid >> 6;
  const int lane = tid & 63;
  const int rowBase = blockIdx.x * 8;

  float acc0 = 0.0f, acc1 = 0.0f;
  for (int kp = 0; kp < EDIM; kp += 64) {
    __syncthreads();
    {  // stage W panel (4096 floats)
      const float4* src = (const float4*)(Wt + (size_t)kp * ALPHA);
      float4* dst = (float4*)&Ws[0][0];
#pragma unroll
      for (int q = 0; q < 4; ++q) dst[tid + q * 256] = src[tid + q * 256];
    }
    if (tid < 128) {  // stage 8 h-rows x 64 k
      int rr = tid >> 4;
      int cc = (tid & 15) << 2;
      *(float4*)&Hs[rr][cc] = *(const float4*)(h + (size_t)(rowBase + rr) * EDIM + kp + cc);
    }
    __syncthreads();
#pragma unroll
    for (int kk = 0; kk < 64; ++kk) {   // ascending k
      float w = Ws[kk][lane];
      acc0 = fmaf(Hs[wave * 2 + 0][kk], w, acc0);
      acc1 = fmaf(Hs[wave * 2 + 1][kk], w, acc1);
    }
  }

  const float ba = b_act[lane];
  const uint32_t k0 = keyA[tstep], k1 = keyB[tstep];
  float logitv[2] = {__fadd_rn(acc0, ba), __fadd_rn(acc1, ba)};

#pragma unroll
  for (int rsel = 0; rsel < 2; ++rsel) {
    const int b = rowBase + wave * 2 + rsel;
    const float logit = logitv[rsel];

    // --- partitionable random_bits: elem m -> threefry(key, (0, m)), xor halves
    uint32_t m = ((uint32_t)b << 6) | (uint32_t)lane;
    uint32_t x0 = 0u, x1 = m;
    threefry2x32(k0, k1, x0, x1);
    uint32_t bits = x0 ^ x1;

    // bit-exact f32 uniform per jax: (bits>>9 | 1.0f) - 1; u = max(tiny, f+tiny)
    float f = __fsub_rn(__uint_as_float((bits >> 9) | 0x3F800000u), 1.0f);
    const float TINY = 1.17549435e-38f;
    float u = fmaxf(TINY, __fadd_rn(f, TINY));
    float gmb = -logf(-logf(u));
    float z = __fadd_rn(logit, gmb);

    // argmax (first index on ties)
    float bv = z;
    int bi = lane;
#pragma unroll
    for (int off = 32; off > 0; off >>= 1) {
      float ov = __shfl_xor(bv, off, 64);
      int oi = __shfl_xor(bi, off, 64);
      if (ov > bv || (ov == bv && oi < bi)) { bv = ov; bi = oi; }
    }

    // log_softmax: shifted - log(sum(exp(shifted)))
    float mx = logit;
#pragma unroll
    for (int off = 32; off > 0; off >>= 1) mx = fmaxf(mx, __shfl_xor(mx, off, 64));
    float sh = __fsub_rn(logit, mx);
    float e = expf(sh);
    float s = e;
#pragma unroll
    for (int off = 32; off > 0; off >>= 1) s = __fadd_rn(s, __shfl_xor(s, off, 64));
    float ls = logf(s);
    float logp = __fsub_rn(sh, ls);

    // entropy term: -sum(exp(logp)*logp)
    float term = __fmul_rn(expf(logp), logp);
    float ts = term;
#pragma unroll
    for (int off = 32; off > 0; off >>= 1) ts = __fadd_rn(ts, __shfl_xor(ts, off, 64));

    float lp_taken = __shfl(logp, bi, 64);  // uses UNMASKED sampled action

    int st = stopped[b];
    float live = st ? 0.0f : 1.0f;
    int act = st ? PAD_TOK : bi;
    int st2 = (st || act == EOS_TOK) ? 1 : 0;

    if (lane == 0) {
      out_msg[(size_t)b * TLEN + tstep] = (float)act;
      out_lp[(size_t)b * TLEN + tstep] = __fmul_rn(lp_taken, live);
      ent_sum[b] += (double)__fmul_rn(-ts, live);
      len_sum[b] += (act != PAD_TOK) ? 1 : 0;
      last[b] = act;
      stopped[b] = st2;
    }
  }
}

__global__ void finalize_kernel(const double* __restrict__ ent_sum,
                                const int* __restrict__ len_sum,
                                float* __restrict__ out_ent, float* __restrict__ out_len) {
  int b = blockIdx.x * 256 + threadIdx.x;
  if (b < BATCH) {
    out_ent[b] = (float)(ent_sum[b] / (double)len_sum[b]);
    out_len[b] = (float)len_sum[b];
  }
}

// ---------------------------------------------------------------------------
extern "C" void kernel_launch(void* const* d_in, const int* in_sizes, int n_in,
                              void* d_out, int out_size, void* d_ws, size_t ws_size,
                              hipStream_t stream) {
  const float* encoded = (const float*)d_in[0];
  const float* embed = (const float*)d_in[1];
  const float* W_ih = (const float*)d_in[2];
  const float* W_hh = (const float*)d_in[3];
  const float* b_ih = (const float*)d_in[4];
  const float* b_hh = (const float*)d_in[5];
  const float* W_cell = (const float*)d_in[6];
  const float* b_cell = (const float*)d_in[7];
  const float* W_hid = (const float*)d_in[8];
  const float* b_hid = (const float*)d_in[9];
  const float* W_act = (const float*)d_in[10];
  const float* b_act = (const float*)d_in[11];

  float* out = (float*)d_out;
  float* out_ent = out;                           // [4096]
  float* out_lp = out + BATCH;                    // [4096*20]
  float* out_msg = out + BATCH + BATCH * TLEN;    // [4096*20]
  float* out_len = out + BATCH + 2 * BATCH * TLEN;// [4096]

  char* ws = (char*)d_ws;
  size_t off = 0;
  auto alloc = [&](size_t bytes) -> void* {
    void* p = ws + off;
    off = (off + bytes + 255) & ~(size_t)255;
    return p;
  };
  float* h = (float*)alloc(sizeof(float) * (size_t)BATCH * EDIM);       // 16 MB
  float* c = (float*)alloc(sizeof(float) * (size_t)BATCH * EDIM);       // 16 MB
  float* gates = (float*)alloc(sizeof(float) * (size_t)BATCH * G4);     // 64 MB
  float* eg = (float*)alloc(sizeof(float) * 66 * G4);                   // 1 MB (raw s1)
  float* Wt = (float*)alloc(sizeof(float) * EDIM * ALPHA);              // 256 KB
  uint32_t* keyA = (uint32_t*)alloc(sizeof(uint32_t) * TLEN);
  uint32_t* keyB = (uint32_t*)alloc(sizeof(uint32_t) * TLEN);
  int* last = (int*)alloc(sizeof(int) * BATCH);
  int* stopped = (int*)alloc(sizeof(int) * BATCH);
  double* ent_s = (double*)alloc(sizeof(double) * BATCH);
  int* len_s = (int*)alloc(sizeof(int) * BATCH);
  int* aliveIdx = (int*)alloc(sizeof(int) * BATCH);
  int* cnt = (int*)alloc(sizeof(int) * TLEN);
  (void)ws_size; (void)in_sizes; (void)n_in; (void)out_size;

  init_kernel<<<16, 256, 0, stream>>>(keyA, keyB, last, stopped, ent_s, len_s, cnt);
  transpose_wact<<<(ALPHA * EDIM) / 256, 256, 0, stream>>>(W_act, Wt);

  // s1 table: eg = embed @ W_ih^T  (NO bias — ref adds bias after both gemms)
  gemm_nt0<<<dim3(32, 1), 256, 0, stream>>>(embed, W_ih, eg, 66, G4, EDIM, nullptr);
  // h0 = encoded @ W_cell^T + b_cell ; c0 = encoded @ W_hid^T + b_hid
  gemm_nt0<<<dim3(8, 32), 256, 0, stream>>>(encoded, W_cell, h, BATCH, EDIM, EDIM, b_cell);
  gemm_nt0<<<dim3(8, 32), 256, 0, stream>>>(encoded, W_hid, c, BATCH, EDIM, EDIM, b_hid);

  for (int t = 0; t < TLEN; ++t) {
    compact_alive<<<16, 256, 0, stream>>>(stopped, aliveIdx, cnt, t);
    // gates[alive] = (eg[last] + h @ W_hh^T) + (b_ih + b_hh)
    gemm_gates<<<dim3(32, 32), 256, 0, stream>>>(h, W_hh, gates, b_ih, b_hh,
                                                 eg, last, aliveIdx, cnt + t);
    lstm_pointwise<<<(BATCH * EDIM) / 256, 256, 0, stream>>>(gates, h, c,
                                                             aliveIdx, cnt + t);
    logits_sample<<<BATCH / 8, 256, 0, stream>>>(h, Wt, b_act, keyA, keyB, t,
                                                 last, stopped, ent_s, len_s,
                                                 out_lp, out_msg);
  }
  finalize_kernel<<<16, 256, 0, stream>>>(ent_s, len_s, out_ent, out_len);
}